// Round 3
// baseline (187020.801 us; speedup 1.0000x reference)
//
#include <hip/hip_runtime.h>

#define TT 512

typedef _Float16 f16;
typedef _Float16 half8 __attribute__((ext_vector_type(8)));
typedef float f32x4 __attribute__((ext_vector_type(4)));

#define MFMA(a,b,c) __builtin_amdgcn_mfma_f32_16x16x32_f16((a),(b),(c),0,0,0)
#define LOSC  2048.0f
#define RLOSC 0.00048828125f   // 1/2048

__device__ __forceinline__ half8 ldh8(const f16* p){ return *(const half8*)p; }
__device__ __forceinline__ float sgm(float x){ return 1.f/(1.f+__expf(-x)); }
// act kinds: 0 tanh, 1 sigmoid, 2 relu, 3 identity
__device__ __forceinline__ float applyact(int k, float x){
  if (k==0) return tanhf(x);
  if (k==1) return sgm(x);
  if (k==2) return fmaxf(x,0.f);
  return x;
}

// ---- grid barrier for 256 blocks: 16 lines x 16 blocks, monotonic counters ----
__device__ __forceinline__ void gbar(unsigned* bar, unsigned ph){
  __syncthreads();
  if (threadIdx.x==0){
    __builtin_amdgcn_fence(__ATOMIC_RELEASE, "agent");
    unsigned g = blockIdx.x & 15u;
    unsigned t = __hip_atomic_fetch_add(&bar[g*32], 1u, __ATOMIC_ACQ_REL, __HIP_MEMORY_SCOPE_AGENT);
    if (t == ph*16u + 15u){                      // last of the 16 blocks on this line
      unsigned d = __hip_atomic_fetch_add(&bar[512], 1u, __ATOMIC_ACQ_REL, __HIP_MEMORY_SCOPE_AGENT);
      if (d == ph*16u + 15u)
        __hip_atomic_store(&bar[544], ph+1u, __ATOMIC_RELEASE, __HIP_MEMORY_SCOPE_AGENT);
    }
    while (__hip_atomic_load(&bar[544], __ATOMIC_ACQUIRE, __HIP_MEMORY_SCOPE_AGENT) <= ph)
      __builtin_amdgcn_s_sleep(1);
    __builtin_amdgcn_fence(__ATOMIC_ACQUIRE, "agent");
  }
  __syncthreads();
}

// ---- per-wave node tile: gate+act 16x16, full K=1024, hi/lo compensated -------
__device__ __forceinline__ void node_wave(
  const f16* __restrict__ AHp, const f16* __restrict__ ALp,   // pred slot base (hi/lo)
  const f16* __restrict__ Whi, const f16* __restrict__ Wlo,   // node weightT base
  float* __restrict__ ST, f16* __restrict__ SH, f16* __restrict__ SL,
  int q, int l15, int mt, int sct,
  int spslot, int outslot, int actkind, bool hl, int wlo)
{
  int m0=mt*16, c0c=sct*16, q8=q*8;
  const f16* Ah = AHp + (m0+l15)*1024 + q8;
  const f16* Al = ALp + (m0+l15)*1024 + q8;
  const f16* Bg = Whi + (c0c+l15)*1024 + q8;
  const f16* Ba = Whi + (1024+c0c+l15)*1024 + q8;
  f32x4 g0={0,0,0,0},g1={0,0,0,0},a0={0,0,0,0},a1={0,0,0,0};
  if (wlo){
    const f16* Bgl = Wlo + (c0c+l15)*1024 + q8;
    const f16* Bal = Wlo + (1024+c0c+l15)*1024 + q8;
    #pragma unroll 4
    for (int k=0;k<1024;k+=32){
      half8 ah=ldh8(Ah+k), al=ldh8(Al+k);
      half8 bg=ldh8(Bg+k), ba=ldh8(Ba+k), bgl=ldh8(Bgl+k), bal=ldh8(Bal+k);
      g0=MFMA(ah,bg,g0); a0=MFMA(ah,ba,a0);
      g1=MFMA(al,bg,g1); g1=MFMA(ah,bgl,g1);
      a1=MFMA(al,ba,a1); a1=MFMA(ah,bal,a1);
    }
  } else {
    #pragma unroll 4
    for (int k=0;k<1024;k+=32){
      half8 ah=ldh8(Ah+k), al=ldh8(Al+k);
      half8 bg=ldh8(Bg+k), ba=ldh8(Ba+k);
      g0=MFMA(ah,bg,g0); a0=MFMA(ah,ba,a0);
      g1=MFMA(al,bg,g1); a1=MFMA(al,ba,a1);
    }
  }
  f32x4 gg = g0 + g1*RLOSC, aa = a0 + a1*RLOSC;
  #pragma unroll
  for (int rr=0;rr<4;rr++){
    int idx = (m0+q*4+rr)*1024 + c0c + l15;
    float sp = ST[spslot*65536+idx];
    float s  = sp + sgm(gg[rr])*(applyact(actkind,aa[rr])-sp);
    ST[outslot*65536+idx]=s;
    if (hl){
      f16 hi=(f16)s; SH[outslot*65536+idx]=hi;
      SL[outslot*65536+idx]=(f16)((s-(float)hi)*LOSC);
    }
  }
}

// ---- fin: sum 4 k-chunk partials, gate/act, write state (1 elem/thread) -------
__device__ __forceinline__ void fin_phase(const float* __restrict__ PART,
  float* __restrict__ ST, f16* __restrict__ SH, f16* __restrict__ SL,
  int b, int tid, int spslot, int outslot, int actkind)
{
  int idx = b*256 + tid;            // 0..65535
  int row = idx>>10, col = idx&1023;
  float gs=0.f, as=0.f;
  #pragma unroll
  for (int kq=0;kq<4;kq++){
    gs += PART[(kq*64+row)*2048 + col];
    as += PART[(kq*64+row)*2048 + 1024 + col];
  }
  float sp = ST[spslot*65536+idx];
  float s  = sp + sgm(gs)*(applyact(actkind,as)-sp);
  ST[outslot*65536+idx]=s;
  f16 hi=(f16)s; SH[outslot*65536+idx]=hi;
  SL[outslot*65536+idx]=(f16)((s-(float)hi)*LOSC);
}

// ------------------------------- persistent kernel ------------------------------
__global__ __launch_bounds__(256,1) void darts_coop(
  const int* __restrict__ X, const float* __restrict__ emb,
  const float* __restrict__ Wout, const float* __restrict__ bout, float* __restrict__ out,
  const f16* __restrict__ W0Th, const f16* __restrict__ W0Tl,
  const f16* __restrict__ WsTh, const f16* __restrict__ WsTl,
  float* __restrict__ ST, f16* __restrict__ SH, f16* __restrict__ SL,
  f16* __restrict__ XNH, f16* __restrict__ XNL,
  float* __restrict__ PART, unsigned* bar, int wlo)
{
  const int tid = threadIdx.x, b = blockIdx.x;
  const int wid = tid>>6, lane = tid&63, q = lane>>4, l15 = lane&15, q8 = q*8;
  __shared__ float xch[2*256];
  unsigned ph = 0;
  const int C0p = wlo? 1536 : 1024;   // P0 stacked-K per chunk (4 chunks)
  const int C1p = wlo? 768  : 512;    // P2 stacked-K per chunk (4 chunks)

  for (int t=0; t<TT; ++t){
    // ---- P0: node0 matmul, stacked [xh_hi*Whi | xh_lo*Whi | (xh_hi*Wlo)], 4 k-chunks
    {
      int sct=b>>2, kq=b&3, m0=wid*16, c0c=sct*16;
      f32x4 g0={0,0,0,0},g1={0,0,0,0},a0={0,0,0,0},a1={0,0,0,0};
      int kk = kq*C0p, kend = kk+C0p;
      while (kk < kend){
        int r = kk>>11, k0 = kk - (r<<11);
        bool inX = k0 < 1024;
        int segEnd = (r<<11) + (inX?1024:2048);
        int seg = ((kend<segEnd)?kend:segEnd) - kk;
        const f16* Abuf = (r==1) ? (inX? XNL : SL) : (inX? XNH : SH); // SH/SL slot0 = h
        int ak = inX? k0 : (k0-1024);
        const f16* Ap = Abuf + (m0+l15)*1024 + ak + q8;
        const f16* Wb = (r==2)? W0Tl : W0Th;
        const f16* Wg = Wb + (c0c+l15)*2048 + k0 + q8;
        const f16* Wa = Wb + (1024+c0c+l15)*2048 + k0 + q8;
        if (r==0){
          #pragma unroll 4
          for (int s=0;s<seg;s+=32){ half8 a=ldh8(Ap+s); g0=MFMA(a,ldh8(Wg+s),g0); a0=MFMA(a,ldh8(Wa+s),a0); }
        } else {
          #pragma unroll 4
          for (int s=0;s<seg;s+=32){ half8 a=ldh8(Ap+s); g1=MFMA(a,ldh8(Wg+s),g1); a1=MFMA(a,ldh8(Wa+s),a1); }
        }
        kk += seg;
      }
      f32x4 gg = g0 + g1*RLOSC, aa = a0 + a1*RLOSC;
      #pragma unroll
      for (int rr=0;rr<4;rr++){
        int row = m0 + q*4 + rr;
        PART[(kq*64+row)*2048 + c0c + l15]        = gg[rr];
        PART[(kq*64+row)*2048 + 1024 + c0c + l15] = aa[rr];
      }
    }
    gbar(bar, ph++);

    // ---- P1: s0 = h + sigm(g)*(tanh(a)-h)
    fin_phase(PART, ST, SH, SL, b, tid, /*sp=h*/0, /*out=s0*/1, /*tanh*/0);
    gbar(bar, ph++);

    // ---- P2: node1 matmul (pred s0, Ws[0]), 4 k-chunks
    {
      int sct=b>>2, kq=b&3, m0=wid*16, c0c=sct*16;
      f32x4 g0={0,0,0,0},g1={0,0,0,0},a0={0,0,0,0},a1={0,0,0,0};
      const f16* AH = SH + 65536;  // s0 hi
      const f16* AL = SL + 65536;
      int kk = kq*C1p, kend = kk+C1p;
      while (kk < kend){
        int r = kk>>10, k0 = kk - (r<<10);
        int segEnd = (r+1)<<10;
        int seg = ((kend<segEnd)?kend:segEnd) - kk;
        const f16* Ap = ((r==1)?AL:AH) + (m0+l15)*1024 + k0 + q8;
        const f16* Wb = (r==2)? WsTl : WsTh;   // node1 -> Ws idx 0
        const f16* Wg = Wb + (c0c+l15)*1024 + k0 + q8;
        const f16* Wa = Wb + (1024+c0c+l15)*1024 + k0 + q8;
        if (r==0){
          #pragma unroll 4
          for (int s=0;s<seg;s+=32){ half8 a=ldh8(Ap+s); g0=MFMA(a,ldh8(Wg+s),g0); a0=MFMA(a,ldh8(Wa+s),a0); }
        } else {
          #pragma unroll 4
          for (int s=0;s<seg;s+=32){ half8 a=ldh8(Ap+s); g1=MFMA(a,ldh8(Wg+s),g1); a1=MFMA(a,ldh8(Wa+s),a1); }
        }
        kk += seg;
      }
      f32x4 gg = g0 + g1*RLOSC, aa = a0 + a1*RLOSC;
      #pragma unroll
      for (int rr=0;rr<4;rr++){
        int row = m0 + q*4 + rr;
        PART[(kq*64+row)*2048 + c0c + l15]        = gg[rr];
        PART[(kq*64+row)*2048 + 1024 + c0c + l15] = aa[rr];
      }
    }
    gbar(bar, ph++);

    // ---- P3: s1 = s0 + sigm(g)*(sigm(a)-s0)
    fin_phase(PART, ST, SH, SL, b, tid, 1, 2, /*sigmoid*/1);
    gbar(bar, ph++);

    // ---- P4: nodes 2,3,4 from s1 (relu, relu, identity); 192 blocks
    if (b < 192){
      int sct = b/3, node = 2 + (b - sct*3);
      node_wave(SH+2*65536, SL+2*65536,
                WsTh + (size_t)(node-1)*2097152, wlo? WsTl + (size_t)(node-1)*2097152 : (const f16*)0,
                ST, SH, SL, q, l15, /*mt*/wid, sct,
                /*sp=s1*/2, /*out*/1+node, (node==4)?3:2, node!=4, wlo);
    }
    gbar(bar, ph++);

    // ---- P5: node5 (tanh, pred s2) & node7 (tanh, pred s3); 128 blocks
    if (b < 128){
      int sct = b>>1, node = (b&1)?7:5;
      int spslot = (node==5)?3:4;
      node_wave(SH+(size_t)spslot*65536, SL+(size_t)spslot*65536,
                WsTh + (size_t)(node-1)*2097152, wlo? WsTl + (size_t)(node-1)*2097152 : (const f16*)0,
                ST, SH, SL, q, l15, wid, sct,
                spslot, 1+node, /*tanh*/0, node==5, wlo);
    }
    gbar(bar, ph++);

    // ---- P6: nodes 6 (sigmoid) & 8 (relu) from s5 + mean -> h; gather x(t+1)
    if (b < 128){
      int sct = b>>1, half = b&1;
      int node = (wid<2)?6:8;
      int mt = half*2 + (wid&1);
      int m0=mt*16, c0c=sct*16;
      const f16* Ah = SH + 6*65536 + (m0+l15)*1024 + q8;   // s5 hi
      const f16* Al = SL + 6*65536 + (m0+l15)*1024 + q8;
      const f16* Bh = WsTh + (size_t)(node-1)*2097152;
      const f16* Bg = Bh + (c0c+l15)*1024 + q8;
      const f16* Ba = Bh + (1024+c0c+l15)*1024 + q8;
      f32x4 g0={0,0,0,0},g1={0,0,0,0},a0={0,0,0,0},a1={0,0,0,0};
      if (wlo){
        const f16* Bl = WsTl + (size_t)(node-1)*2097152;
        const f16* Bgl = Bl + (c0c+l15)*1024 + q8;
        const f16* Bal = Bl + (1024+c0c+l15)*1024 + q8;
        #pragma unroll 4
        for (int k=0;k<1024;k+=32){
          half8 ah=ldh8(Ah+k), al=ldh8(Al+k);
          g0=MFMA(ah,ldh8(Bg+k),g0); a0=MFMA(ah,ldh8(Ba+k),a0);
          g1=MFMA(al,ldh8(Bg+k),g1); g1=MFMA(ah,ldh8(Bgl+k),g1);
          a1=MFMA(al,ldh8(Ba+k),a1); a1=MFMA(ah,ldh8(Bal+k),a1);
        }
      } else {
        #pragma unroll 4
        for (int k=0;k<1024;k+=32){
          half8 ah=ldh8(Ah+k), al=ldh8(Al+k);
          half8 bg=ldh8(Bg+k), ba=ldh8(Ba+k);
          g0=MFMA(ah,bg,g0); a0=MFMA(ah,ba,a0);
          g1=MFMA(al,bg,g1); a1=MFMA(al,ba,a1);
        }
      }
      f32x4 gg = g0 + g1*RLOSC, aa = a0 + a1*RLOSC;
      float sv[4];
      #pragma unroll
      for (int rr=0;rr<4;rr++){
        int idx = (m0+q*4+rr)*1024 + c0c + l15;
        float sp = ST[6*65536+idx];
        float av = (node==6)? sgm(aa[rr]) : fmaxf(aa[rr],0.f);
        sv[rr] = sp + sgm(gg[rr])*(av-sp);
      }
      if (wid>=2){   // node8 waves: publish s8 tiles
        #pragma unroll
        for (int rr=0;rr<4;rr++) xch[(wid-2)*256 + (q*4+rr)*16 + l15] = sv[rr];
      }
      __syncthreads();
      if (wid<2){    // node6 waves: mean of s1..s8 -> h
        #pragma unroll
        for (int rr=0;rr<4;rr++){
          int idx = (m0+q*4+rr)*1024 + c0c + l15;
          float s8 = xch[wid*256 + (q*4+rr)*16 + l15];
          float m = (ST[2*65536+idx]+ST[3*65536+idx]+ST[4*65536+idx]+ST[5*65536+idx]
                    +ST[6*65536+idx]+ST[8*65536+idx]+sv[rr]+s8)*0.125f;
          ST[idx]=m;
          f16 hi=(f16)m; SH[idx]=hi; SL[idx]=(f16)((m-(float)hi)*LOSC);
        }
      }
    } else {
      // blocks 128..255: gather next-step embedding (hi/lo split)
      if (t+1 < TT){
        int base = (b-128)*512 + tid;
        #pragma unroll
        for (int u=0;u<2;u++){
          int idx = base + u*256;
          int brow = idx>>10, k = idx&1023;
          int tok = X[(t+1)*64 + brow];
          float v = emb[tok*1024 + k];
          f16 hi=(f16)v; XNH[idx]=hi; XNL[idx]=(f16)((v-(float)hi)*LOSC);
        }
      }
    }
    gbar(bar, ph++);
  }

  // ---- final head: a_hat = h @ Wout + bout ; probs = softmax (b==0, 256 thr)
  if (b==0){
    int row = tid>>2, col = tid&3;
    float acc = bout[col];
    const float* hrow = ST + row*1024;
    #pragma unroll 8
    for (int k=0;k<1024;k++) acc += hrow[k]*Wout[k*4+col];
    out[row*4+col] = acc;
    float m = fmaxf(acc, __shfl_xor(acc,1));
    m = fmaxf(m, __shfl_xor(m,2));
    float e = __expf(acc-m);
    float ssum = e + __shfl_xor(e,1);
    ssum = ssum + __shfl_xor(ssum,2);
    out[256 + row*4+col] = e/ssum;
  }
}

// ------------------------------- prep kernels -----------------------------------
__global__ void prep_x0(const int* __restrict__ X, const float* __restrict__ hidden,
  const float* __restrict__ emb, f16* __restrict__ XNH, f16* __restrict__ XNL,
  float* __restrict__ ST, f16* __restrict__ SH, f16* __restrict__ SL, unsigned* bar)
{
  int idx = blockIdx.x*256 + threadIdx.x;   // 65536 threads
  float hv = hidden[idx];
  ST[idx] = hv;
  f16 hh=(f16)hv; SH[idx]=hh; SL[idx]=(f16)((hv-(float)hh)*LOSC);
  int brow = idx>>10, k = idx&1023;
  int tok = X[brow];
  float v = emb[tok*1024+k];
  f16 xh=(f16)v; XNH[idx]=xh; XNL[idx]=(f16)((v-(float)xh)*LOSC);
  if (idx < 1024) bar[idx] = 0u;
}

__global__ void prep_w(const float* __restrict__ W0, const float* __restrict__ Ws,
  f16* __restrict__ W0Th, f16* __restrict__ W0Tl, f16* __restrict__ WsTh, f16* __restrict__ WsTl)
{
  __shared__ float L[64][65];
  int b = blockIdx.x, tid = threadIdx.x;
  const float* src; f16 *Dh, *Dl; int K, tk, tn;
  if (b < 1024){ src=W0; Dh=W0Th; Dl=W0Tl; K=2048; tk=b&31; tn=b>>5; }
  else { int bb=b-1024; int mi=bb>>9; int t2=bb&511; tk=t2&15; tn=t2>>4;
         src = Ws + (size_t)mi*1024*2048; Dh = WsTh + (size_t)mi*2097152;
         Dl = WsTl ? (WsTl + (size_t)mi*2097152) : (f16*)0; K=1024; }
  int k0 = tk*64, n0 = tn*64;
  int rr = tid>>6, cc = tid&63;
  #pragma unroll
  for (int j=0;j<16;j++){
    int r = j*4 + rr;
    L[cc][r] = src[(size_t)(k0+r)*2048 + n0+cc];
  }
  __syncthreads();
  #pragma unroll
  for (int j=0;j<16;j++){
    int n = j*4 + rr;
    float v = L[n][cc];
    f16 hi = (f16)v;
    Dh[(size_t)(n0+n)*K + k0+cc] = hi;
    if (Dl) Dl[(size_t)(n0+n)*K + k0+cc] = (f16)((v-(float)hi)*LOSC);
  }
}

__global__ void sentinel_k(float* __restrict__ out, float v){
  int i = blockIdx.x*256 + threadIdx.x;
  if (i < 512) out[i] = v;
}

// ------------------------------- launcher ----------------------------------------
extern "C" void kernel_launch(void* const* d_in, const int* in_sizes, int n_in,
                              void* d_out, int out_size, void* d_ws, size_t ws_size,
                              hipStream_t stream)
{
  const int*   X      = (const int*)  d_in[0];
  const float* hidden = (const float*)d_in[1];
  const float* emb    = (const float*)d_in[2];
  const float* W0     = (const float*)d_in[3];
  const float* Ws     = (const float*)d_in[4];
  const float* Wout   = (const float*)d_in[5];
  const float* bout   = (const float*)d_in[6];
  float* out = (float*)d_out;

  const size_t SZ_W0   = (size_t)2048*2048*2;      // 8.39 MB (f16)
  const size_t SZ_WS   = (size_t)8*2048*1024*2;    // 33.55 MB
  const size_t SZ_ST   = (size_t)10*65536*4;
  const size_t SZ_SHL  = (size_t)10*65536*2;
  const size_t SZ_XN   = (size_t)65536*2;
  const size_t SZ_PART = (size_t)4*64*2048*4;      // 2 MB
  const size_t SZ_BAR  = 4096;

  auto pad = [](size_t x){ return (x + 255) & ~(size_t)255; };
  size_t need_red  = pad(SZ_W0) + pad(SZ_WS) + pad(SZ_ST) + 2*pad(SZ_SHL)
                   + 2*pad(SZ_XN) + pad(SZ_PART) + pad(SZ_BAR);
  size_t need_full = need_red + pad(SZ_W0) + pad(SZ_WS);

  int wlo;
  if (ws_size >= need_full)      wlo = 1;
  else if (ws_size >= need_red)  wlo = 0;
  else { hipLaunchKernelGGL(sentinel_k, dim3(2), dim3(256), 0, stream, out, 1.0e6f); return; }

  char* w = (char*)d_ws; size_t off = 0;
  auto alloc = [&](size_t bytes)->void*{ void* p = w+off; off += (bytes+255)&~(size_t)255; return p; };
  f16* W0Th = (f16*)alloc(SZ_W0);
  f16* WsTh = (f16*)alloc(SZ_WS);
  f16* W0Tl = wlo ? (f16*)alloc(SZ_W0) : (f16*)0;
  f16* WsTl = wlo ? (f16*)alloc(SZ_WS) : (f16*)0;
  float* ST = (float*)alloc(SZ_ST);
  f16* SH   = (f16*)alloc(SZ_SHL);
  f16* SL   = (f16*)alloc(SZ_SHL);
  f16* XNH  = (f16*)alloc(SZ_XN);
  f16* XNL  = (f16*)alloc(SZ_XN);
  float* PART = (float*)alloc(SZ_PART);
  unsigned* bar = (unsigned*)alloc(SZ_BAR);

  hipLaunchKernelGGL(prep_x0, dim3(256), dim3(256), 0, stream,
                     X, hidden, emb, XNH, XNL, ST, SH, SL, bar);
  hipLaunchKernelGGL(prep_w, dim3(5120), dim3(256), 0, stream,
                     W0, Ws, W0Th, W0Tl, WsTh, WsTl);

  // 256 blocks: min occupancy is 1 block/CU on 256 CUs, so a cooperative grid
  // of 256 always fits; fall back to a plain launch if coop is unavailable.
  void* args[] = { (void*)&X, (void*)&emb, (void*)&Wout, (void*)&bout, (void*)&out,
                   (void*)&W0Th, (void*)&W0Tl, (void*)&WsTh, (void*)&WsTl,
                   (void*)&ST, (void*)&SH, (void*)&SL, (void*)&XNH, (void*)&XNL,
                   (void*)&PART, (void*)&bar, (void*)&wlo };
  hipError_t e = hipLaunchCooperativeKernel((void*)darts_coop, dim3(256), dim3(256), args, 0, stream);
  if (e != hipSuccess){
    hipLaunchKernelGGL(darts_coop, dim3(256), dim3(256), 0, stream,
                       X, emb, Wout, bout, out, W0Th, W0Tl, WsTh, WsTl,
                       ST, SH, SL, XNH, XNL, PART, bar, wlo);
  }
}

// Round 4
// 80363.507 us; speedup vs baseline: 2.3272x; 2.3272x over previous
//
#include <hip/hip_runtime.h>

#define TT 512

typedef _Float16 f16;
typedef _Float16 half8 __attribute__((ext_vector_type(8)));
typedef float f32x4 __attribute__((ext_vector_type(4)));

#define MFMA(a,b,c) __builtin_amdgcn_mfma_f32_16x16x32_f16((a),(b),(c),0,0,0)
#define LOSC  2048.0f
#define RLOSC 0.00048828125f   // 1/2048

__device__ __forceinline__ half8 ldh8(const f16* p){ return *(const half8*)p; }
__device__ __forceinline__ float sgm(float x){ return 1.f/(1.f+__expf(-x)); }
// act kinds: 0 tanh, 1 sigmoid, 2 relu, 3 identity
__device__ __forceinline__ float applyact(int k, float x){
  if (k==0) return tanhf(x);
  if (k==1) return sgm(x);
  if (k==2) return fmaxf(x,0.f);
  return x;
}

// ---- grid barrier for 256 blocks: 16 lines x 16 blocks, monotonic counters ----
__device__ __forceinline__ void gbar(unsigned* bar, unsigned ph){
  __syncthreads();
  if (threadIdx.x==0){
    __builtin_amdgcn_fence(__ATOMIC_RELEASE, "agent");
    unsigned g = blockIdx.x & 15u;
    unsigned t = __hip_atomic_fetch_add(&bar[g*32], 1u, __ATOMIC_ACQ_REL, __HIP_MEMORY_SCOPE_AGENT);
    if (t == ph*16u + 15u){
      unsigned d = __hip_atomic_fetch_add(&bar[512], 1u, __ATOMIC_ACQ_REL, __HIP_MEMORY_SCOPE_AGENT);
      if (d == ph*16u + 15u)
        __hip_atomic_store(&bar[544], ph+1u, __ATOMIC_RELEASE, __HIP_MEMORY_SCOPE_AGENT);
    }
    while (__hip_atomic_load(&bar[544], __ATOMIC_RELAXED, __HIP_MEMORY_SCOPE_AGENT) <= ph)
      __builtin_amdgcn_s_sleep(1);
    __builtin_amdgcn_fence(__ATOMIC_ACQUIRE, "agent");
  }
  __syncthreads();
}

// ---- per-wave K-slice of a node matmul (K=1024, stacked hi/lo), LDS partials ---
__device__ __forceinline__ void node_task(
  const f16* __restrict__ AH, const f16* __restrict__ AL,
  const f16* __restrict__ Wh, const f16* __restrict__ Wl,
  float* __restrict__ Lg, float* __restrict__ La,
  int wid, int q, int l15, int mt, int sct, int wlo)
{
  int q8=q*8, m0=mt*16, c0=sct*16;
  const int per = wlo? 192 : 128;         // stacked K (3072|2048) / 16 waves
  int kk = wid*per, kend = kk+per;
  f32x4 g0={0,0,0,0},g1={0,0,0,0},a0={0,0,0,0},a1={0,0,0,0};
  while (kk<kend){
    int r = kk>>10, k0 = kk&1023;
    int segEnd = (r+1)<<10;
    int seg = ((kend<segEnd)?kend:segEnd) - kk;
    const f16* Ap = ((r==1)?AL:AH) + (m0+l15)*1024 + k0 + q8;
    const f16* Wb = (r==2)? Wl : Wh;
    const f16* Bg = Wb + (c0+l15)*1024 + k0 + q8;
    const f16* Ba = Wb + (1024+c0+l15)*1024 + k0 + q8;
    if (r==0){
      #pragma unroll 2
      for (int s=0;s<seg;s+=32){ half8 a=ldh8(Ap+s); g0=MFMA(a,ldh8(Bg+s),g0); a0=MFMA(a,ldh8(Ba+s),a0); }
    } else {
      #pragma unroll 2
      for (int s=0;s<seg;s+=32){ half8 a=ldh8(Ap+s); g1=MFMA(a,ldh8(Bg+s),g1); a1=MFMA(a,ldh8(Ba+s),a1); }
    }
    kk+=seg;
  }
  f32x4 gg = g0 + g1*RLOSC, aa = a0 + a1*RLOSC;
  #pragma unroll
  for (int rr=0;rr<4;rr++){
    int e = (q*4+rr)*16 + l15;
    Lg[wid*256+e] = gg[rr];
    La[wid*256+e] = aa[rr];
  }
}

// ---- reduce 16 wave partials, apply gate/act, write state tile ----------------
__device__ __forceinline__ void fin_write(const float* __restrict__ Lg, const float* __restrict__ La,
  float* __restrict__ ST, f16* __restrict__ SH, f16* __restrict__ SL,
  int tid, int mt, int sct, int spslot, int outslot, int actkind, bool hl)
{
  if (tid < 256){
    float gs=0.f, as=0.f;
    #pragma unroll
    for (int j=0;j<16;j++){ gs+=Lg[j*256+tid]; as+=La[j*256+tid]; }
    int idx = (mt*16+(tid>>4))*1024 + sct*16 + (tid&15);
    float sp = ST[spslot*65536+idx];
    float s = sp + sgm(gs)*(applyact(actkind,as)-sp);
    ST[outslot*65536+idx] = s;
    if (hl){ f16 hi=(f16)s; SH[outslot*65536+idx]=hi; SL[outslot*65536+idx]=(f16)((s-(float)hi)*LOSC); }
  }
}

// ------------------------------- persistent kernel ------------------------------
__global__ __launch_bounds__(1024,4) void darts_coop(
  const int* __restrict__ X, const float* __restrict__ emb,
  const float* __restrict__ Wout, const float* __restrict__ bout, float* __restrict__ out,
  const f16* __restrict__ W0Th, const f16* __restrict__ W0Tl,
  const f16* __restrict__ WsTh, const f16* __restrict__ WsTl,
  float* __restrict__ ST, f16* __restrict__ SH, f16* __restrict__ SL,
  f16* __restrict__ XNH, f16* __restrict__ XNL,
  unsigned* bar, int wlo)
{
  const int tid = threadIdx.x, b = blockIdx.x;
  const int wid = tid>>6, lane = tid&63, q = lane>>4, l15 = lane&15, q8 = q*8;
  const int mt = b&3, sct = b>>2;           // this block's 16x16 tile (rows, cols)
  __shared__ float Lg[4096], La[4096];      // 16 wave-partials x 256 elems
  unsigned ph = 0;

  for (int t=0; t<TT; ++t){
    // ---- P0: node0, stacked K = [xh_hi*Whi | xh_lo*Whi | (xh_hi*Wlo)] ----------
    {
      int m0=mt*16, c0=sct*16;
      const int per = wlo? 384 : 256;       // (6144|4096)/16
      int kk = wid*per, kend = kk+per;
      f32x4 g0={0,0,0,0},g1={0,0,0,0},a0={0,0,0,0},a1={0,0,0,0};
      while (kk<kend){
        int r = kk>>11, k0 = kk - (r<<11);
        bool inX = k0 < 1024;
        int segEnd = (r<<11) + (inX?1024:2048);
        int seg = ((kend<segEnd)?kend:segEnd) - kk;
        const f16* Abuf = (r==1) ? (inX? XNL : SL) : (inX? XNH : SH);  // slot0 = h
        int ak = inX? k0 : (k0-1024);
        const f16* Ap = Abuf + (m0+l15)*1024 + ak + q8;
        const f16* Wb = (r==2)? W0Tl : W0Th;
        const f16* Bg = Wb + (c0+l15)*2048 + k0 + q8;
        const f16* Ba = Wb + (1024+c0+l15)*2048 + k0 + q8;
        if (r==0){
          #pragma unroll 2
          for (int s=0;s<seg;s+=32){ half8 a=ldh8(Ap+s); g0=MFMA(a,ldh8(Bg+s),g0); a0=MFMA(a,ldh8(Ba+s),a0); }
        } else {
          #pragma unroll 2
          for (int s=0;s<seg;s+=32){ half8 a=ldh8(Ap+s); g1=MFMA(a,ldh8(Bg+s),g1); a1=MFMA(a,ldh8(Ba+s),a1); }
        }
        kk += seg;
      }
      f32x4 gg = g0 + g1*RLOSC, aa = a0 + a1*RLOSC;
      #pragma unroll
      for (int rr=0;rr<4;rr++){
        int e = (q*4+rr)*16 + l15;
        Lg[wid*256+e] = gg[rr];
        La[wid*256+e] = aa[rr];
      }
    }
    __syncthreads();
    fin_write(Lg, La, ST, SH, SL, tid, mt, sct, /*sp=h*/0, /*out=s0*/1, /*tanh*/0, true);
    gbar(bar, ph++);

    // ---- P2: node1 (pred s0, Ws[0], sigmoid) + next-x gather on idle threads ---
    node_task(SH+65536, SL+65536, WsTh, WsTl, Lg, La, wid, q, l15, mt, sct, wlo);
    if (t+1 < TT && tid >= 256 && tid < 512){
      int idx = b*256 + (tid-256);
      int brow = idx>>10, k = idx&1023;
      int tok = X[(t+1)*64 + brow];
      float v = emb[tok*1024 + k];
      f16 hi=(f16)v; XNH[idx]=hi; XNL[idx]=(f16)((v-(float)hi)*LOSC);
    }
    __syncthreads();
    fin_write(Lg, La, ST, SH, SL, tid, mt, sct, 1, 2, /*sigmoid*/1, true);
    gbar(bar, ph++);

    // ---- P4: nodes 2,3,4 from s1 (relu, relu, identity), sequential -----------
    for (int i=0;i<3;i++){
      int node = 2+i;
      __syncthreads();
      node_task(SH+2*65536, SL+2*65536,
                WsTh + (size_t)(node-1)*2097152,
                wlo? WsTl + (size_t)(node-1)*2097152 : (const f16*)0,
                Lg, La, wid, q, l15, mt, sct, wlo);
      __syncthreads();
      fin_write(Lg, La, ST, SH, SL, tid, mt, sct, 2, 1+node, (node==4)?3:2, node!=4);
    }
    gbar(bar, ph++);

    // ---- P5: node5 (tanh, pred s2) then node7 (tanh, pred s3) -----------------
    node_task(SH+3*65536, SL+3*65536, WsTh + (size_t)4*2097152,
              wlo? WsTl + (size_t)4*2097152 : (const f16*)0,
              Lg, La, wid, q, l15, mt, sct, wlo);
    __syncthreads();
    fin_write(Lg, La, ST, SH, SL, tid, mt, sct, 3, 6, /*tanh*/0, true);
    __syncthreads();
    node_task(SH+4*65536, SL+4*65536, WsTh + (size_t)6*2097152,
              wlo? WsTl + (size_t)6*2097152 : (const f16*)0,
              Lg, La, wid, q, l15, mt, sct, wlo);
    __syncthreads();
    fin_write(Lg, La, ST, SH, SL, tid, mt, sct, 4, 8, /*tanh*/0, false);
    gbar(bar, ph++);

    // ---- P6: node6 (sigmoid) & node8 (relu) from s5, mean -> h ----------------
    node_task(SH+6*65536, SL+6*65536, WsTh + (size_t)5*2097152,
              wlo? WsTl + (size_t)5*2097152 : (const f16*)0,
              Lg, La, wid, q, l15, mt, sct, wlo);
    __syncthreads();
    float s6v = 0.f;
    if (tid < 256){
      float gs=0.f, as=0.f;
      #pragma unroll
      for (int j=0;j<16;j++){ gs+=Lg[j*256+tid]; as+=La[j*256+tid]; }
      int idx = (mt*16+(tid>>4))*1024 + sct*16 + (tid&15);
      float sp = ST[6*65536+idx];
      s6v = sp + sgm(gs)*(sgm(as)-sp);
    }
    __syncthreads();
    node_task(SH+6*65536, SL+6*65536, WsTh + (size_t)7*2097152,
              wlo? WsTl + (size_t)7*2097152 : (const f16*)0,
              Lg, La, wid, q, l15, mt, sct, wlo);
    __syncthreads();
    if (tid < 256){
      float gs=0.f, as=0.f;
      #pragma unroll
      for (int j=0;j<16;j++){ gs+=Lg[j*256+tid]; as+=La[j*256+tid]; }
      int idx = (mt*16+(tid>>4))*1024 + sct*16 + (tid&15);
      float sp = ST[6*65536+idx];
      float s8v = sp + sgm(gs)*(fmaxf(as,0.f)-sp);
      float m = (ST[2*65536+idx]+ST[3*65536+idx]+ST[4*65536+idx]+ST[5*65536+idx]
                +ST[6*65536+idx]+ST[8*65536+idx]+s6v+s8v)*0.125f;
      ST[idx]=m;
      f16 hi=(f16)m; SH[idx]=hi; SL[idx]=(f16)((m-(float)hi)*LOSC);
    }
    gbar(bar, ph++);
  }

  // ---- final head: a_hat = h @ Wout + bout ; probs = softmax --------------------
  if (b==0 && tid<256){
    int row = tid>>2, col = tid&3;
    float acc = bout[col];
    const float* hrow = ST + row*1024;
    #pragma unroll 8
    for (int k=0;k<1024;k++) acc += hrow[k]*Wout[k*4+col];
    out[row*4+col] = acc;
    float m = fmaxf(acc, __shfl_xor(acc,1));
    m = fmaxf(m, __shfl_xor(m,2));
    float e = __expf(acc-m);
    float ssum = e + __shfl_xor(e,1);
    ssum = ssum + __shfl_xor(ssum,2);
    out[256 + row*4+col] = e/ssum;
  }
}

// ------------------------------- prep kernels -----------------------------------
__global__ void prep_x0(const int* __restrict__ X, const float* __restrict__ hidden,
  const float* __restrict__ emb, f16* __restrict__ XNH, f16* __restrict__ XNL,
  float* __restrict__ ST, f16* __restrict__ SH, f16* __restrict__ SL, unsigned* bar)
{
  int idx = blockIdx.x*256 + threadIdx.x;   // 65536 threads
  float hv = hidden[idx];
  ST[idx] = hv;
  f16 hh=(f16)hv; SH[idx]=hh; SL[idx]=(f16)((hv-(float)hh)*LOSC);
  int brow = idx>>10, k = idx&1023;
  int tok = X[brow];
  float v = emb[tok*1024+k];
  f16 xh=(f16)v; XNH[idx]=xh; XNL[idx]=(f16)((v-(float)xh)*LOSC);
  if (idx < 1024) bar[idx] = 0u;
}

__global__ void prep_w(const float* __restrict__ W0, const float* __restrict__ Ws,
  f16* __restrict__ W0Th, f16* __restrict__ W0Tl, f16* __restrict__ WsTh, f16* __restrict__ WsTl)
{
  __shared__ float L[64][65];
  int b = blockIdx.x, tid = threadIdx.x;
  const float* src; f16 *Dh, *Dl; int K, tk, tn;
  if (b < 1024){ src=W0; Dh=W0Th; Dl=W0Tl; K=2048; tk=b&31; tn=b>>5; }
  else { int bb=b-1024; int mi=bb>>9; int t2=bb&511; tk=t2&15; tn=t2>>4;
         src = Ws + (size_t)mi*1024*2048; Dh = WsTh + (size_t)mi*2097152;
         Dl = WsTl ? (WsTl + (size_t)mi*2097152) : (f16*)0; K=1024; }
  int k0 = tk*64, n0 = tn*64;
  int rr = tid>>6, cc = tid&63;
  #pragma unroll
  for (int j=0;j<16;j++){
    int r = j*4 + rr;
    L[cc][r] = src[(size_t)(k0+r)*2048 + n0+cc];
  }
  __syncthreads();
  #pragma unroll
  for (int j=0;j<16;j++){
    int n = j*4 + rr;
    float v = L[n][cc];
    f16 hi = (f16)v;
    Dh[(size_t)(n0+n)*K + k0+cc] = hi;
    if (Dl) Dl[(size_t)(n0+n)*K + k0+cc] = (f16)((v-(float)hi)*LOSC);
  }
}

__global__ void sentinel_k(float* __restrict__ out, float v){
  int i = blockIdx.x*256 + threadIdx.x;
  if (i < 512) out[i] = v;
}

// ------------------------------- launcher ----------------------------------------
extern "C" void kernel_launch(void* const* d_in, const int* in_sizes, int n_in,
                              void* d_out, int out_size, void* d_ws, size_t ws_size,
                              hipStream_t stream)
{
  const int*   X      = (const int*)  d_in[0];
  const float* hidden = (const float*)d_in[1];
  const float* emb    = (const float*)d_in[2];
  const float* W0     = (const float*)d_in[3];
  const float* Ws     = (const float*)d_in[4];
  const float* Wout   = (const float*)d_in[5];
  const float* bout   = (const float*)d_in[6];
  float* out = (float*)d_out;

  const size_t SZ_W0   = (size_t)2048*2048*2;      // 8.39 MB (f16)
  const size_t SZ_WS   = (size_t)8*2048*1024*2;    // 33.55 MB
  const size_t SZ_ST   = (size_t)10*65536*4;
  const size_t SZ_SHL  = (size_t)10*65536*2;
  const size_t SZ_XN   = (size_t)65536*2;
  const size_t SZ_BAR  = 4096;

  auto pad = [](size_t x){ return (x + 255) & ~(size_t)255; };
  size_t need_red  = pad(SZ_W0) + pad(SZ_WS) + pad(SZ_ST) + 2*pad(SZ_SHL)
                   + 2*pad(SZ_XN) + pad(SZ_BAR);
  size_t need_full = need_red + pad(SZ_W0) + pad(SZ_WS);

  int wlo;
  if (ws_size >= need_full)      wlo = 1;
  else if (ws_size >= need_red)  wlo = 0;
  else { hipLaunchKernelGGL(sentinel_k, dim3(2), dim3(256), 0, stream, out, 1.0e6f); return; }

  char* w = (char*)d_ws; size_t off = 0;
  auto alloc = [&](size_t bytes)->void*{ void* p = w+off; off += (bytes+255)&~(size_t)255; return p; };
  f16* W0Th = (f16*)alloc(SZ_W0);
  f16* WsTh = (f16*)alloc(SZ_WS);
  f16* W0Tl = wlo ? (f16*)alloc(SZ_W0) : (f16*)0;
  f16* WsTl = wlo ? (f16*)alloc(SZ_WS) : (f16*)0;
  float* ST = (float*)alloc(SZ_ST);
  f16* SH   = (f16*)alloc(SZ_SHL);
  f16* SL   = (f16*)alloc(SZ_SHL);
  f16* XNH  = (f16*)alloc(SZ_XN);
  f16* XNL  = (f16*)alloc(SZ_XN);
  unsigned* bar = (unsigned*)alloc(SZ_BAR);

  hipLaunchKernelGGL(prep_x0, dim3(256), dim3(256), 0, stream,
                     X, hidden, emb, XNH, XNL, ST, SH, SL, bar);
  hipLaunchKernelGGL(prep_w, dim3(5120), dim3(256), 0, stream,
                     W0, Ws, W0Th, W0Tl, WsTh, WsTl);

  // 256 blocks x 1024 threads: 1 block/CU on 256 CUs -> co-residency guaranteed.
  void* args[] = { (void*)&X, (void*)&emb, (void*)&Wout, (void*)&bout, (void*)&out,
                   (void*)&W0Th, (void*)&W0Tl, (void*)&WsTh, (void*)&WsTl,
                   (void*)&ST, (void*)&SH, (void*)&SL, (void*)&XNH, (void*)&XNL,
                   (void*)&bar, (void*)&wlo };
  hipError_t e = hipLaunchCooperativeKernel((void*)darts_coop, dim3(256), dim3(1024), args, 0, stream);
  if (e != hipSuccess){
    hipLaunchKernelGGL(darts_coop, dim3(256), dim3(1024), 0, stream,
                       X, emb, Wout, bout, out, W0Th, W0Tl, WsTh, WsTl,
                       ST, SH, SL, XNH, XNL, bar, wlo);
  }
}